// Round 8
// baseline (162.178 us; speedup 1.0000x reference)
//
#include <hip/hip_runtime.h>
#include <hip/hip_fp16.h>

// out = sa*sb * (x @ q_b) @ q_a^T + bias
// GEMM1 (split-K=4, deep pipeline): P[z] = x[:,z-chunk] @ q_b-chunk (f16 partials)
//   BM=128 BN=256 BK=32, 512 thr / 8 waves (2m x 4n, wave tile 64x64, acc[4][4]).
//   B: gload_lds, TRIPLE-buffered, depth 2 (L2 latency hidden).
//   A: f32->f16 reg-staged, 4 named reg sets, depth ~3 (HBM latency hidden).
//   Counted vmcnt(4) steady state - never drain to 0 except last 4 iters.
// reduce: t = f16(sum_z P[z]);  GEMM2 unchanged (counted-vmcnt dbuf 128x128).

#define M_TOT 8192
#define N_OUT 4096
#define K_IN  4096
#define RANK  512

typedef _Float16 f16x8 __attribute__((ext_vector_type(8)));
typedef float f32x4 __attribute__((ext_vector_type(4)));

#define WAIT_VM0() asm volatile("s_waitcnt vmcnt(0)" ::: "memory")
#define WAIT_VM2() asm volatile("s_waitcnt vmcnt(2)" ::: "memory")
#define WAIT_VM4() asm volatile("s_waitcnt vmcnt(4)" ::: "memory")
#define WAIT_VM8() asm volatile("s_waitcnt vmcnt(8)" ::: "memory")
#define WAIT_LGKM0() asm volatile("s_waitcnt lgkmcnt(0)" ::: "memory")
#define BARRIER() do { __builtin_amdgcn_s_barrier(); __builtin_amdgcn_sched_barrier(0); } while (0)

__device__ __forceinline__ void gload_lds16(const void* g, void* l) {
  __builtin_amdgcn_global_load_lds(
      (const __attribute__((address_space(1))) unsigned int*)g,
      (__attribute__((address_space(3))) unsigned int*)l, 16, 0, 0);
}

// paired-row LDS layout: logical (row r, slot s in 0..3) ->
// phys uint4 idx = (r>>1)*8 + ((((r&1)<<2)|s) ^ ((r>>1)&7))   [2-way reads = free]
__device__ __forceinline__ int lds_idx(int r, int s) {
  return (r >> 1) * 8 + (((((r & 1) << 2) | s)) ^ ((r >> 1) & 7));
}

// ---- convert q_a int32 -> fp16 ----
__global__ void k_cvt_qa(const int4* __restrict__ q, ushort4* __restrict__ o, int n4) {
  int i = blockIdx.x * blockDim.x + threadIdx.x;
  if (i >= n4) return;
  int4 v = q[i];
  ushort4 r;
  r.x = __half_as_ushort(__float2half_rn((float)v.x));
  r.y = __half_as_ushort(__float2half_rn((float)v.y));
  r.z = __half_as_ushort(__float2half_rn((float)v.z));
  r.w = __half_as_ushort(__float2half_rn((float)v.w));
  o[i] = r;
}

// ---- transpose q_b [K_IN][RANK] i32 -> qbt [RANK][K_IN] fp16 ----
__global__ void k_transpose_qb(const int* __restrict__ qb, __half* __restrict__ qbt) {
  __shared__ __half tile[32][33];
  int tx = threadIdx.x & 31, ty = threadIdx.x >> 5;
  int k0 = blockIdx.x * 32, r0 = blockIdx.y * 32;
#pragma unroll
  for (int j = 0; j < 4; ++j)
    tile[ty + j * 8][tx] = __float2half_rn((float)qb[(size_t)(k0 + ty + j * 8) * RANK + r0 + tx]);
  __syncthreads();
#pragma unroll
  for (int j = 0; j < 4; ++j)
    qbt[(size_t)(r0 + ty + j * 8) * K_IN + k0 + tx] = tile[tx][ty + j * 8];
}

// ---- GEMM1 deep-pipelined split-K ----
__global__ __launch_bounds__(512, 2) void k_gemm1_sk(
    const float* __restrict__ X, const __half* __restrict__ Bt,
    __half* __restrict__ P) {
  // [0,512)=A buf0, [512,1024)=A buf1, [1024+1024*b) = B buf b (b=0..2)
  __shared__ __align__(16) uint4 lds[4096];  // 64 KB
  const int tid = threadIdx.x;
  const int lane = tid & 63, wid = tid >> 6;
  const int wm = wid & 1, wn = wid >> 1;           // 2m x 4n waves
  const int blk = blockIdx.x;
  const int xcd = blk & 7, m_t = blk >> 3;         // m_t 0..63
  const int z = xcd >> 1, n_t = xcd & 1;           // xcd owns (z, n_t): qbt panel L2-hot
  const int m0 = m_t * 128, n0 = n_t * 256;
  const int kbeg = z * (K_IN / 4);
  const int fr = lane & 15, fq = lane >> 4;
  const int NT = (K_IN / 4) / 32;                  // 32 K-steps

  f32x4 acc[4][4] = {};

  // A staging: thread -> row ar = tid>>2 (0..127), 8 floats at col aq*8
  const int ar = tid >> 2, aq = tid & 3;
  const float* xrow = X + (size_t)(m0 + ar) * K_IN + kbeg + aq * 8;
  const int aidx = lds_idx(ar, aq);
  // B staging: 2 gload_lds/thread, linear phys dest, inverse-swizzled source
  const __half* bsrc0; const __half* bsrc1; int bd0, bd1;
  {
    int d0 = tid, d1 = tid + 512;
    int p0 = d0 >> 3, u0 = (d0 & 7) ^ (p0 & 7);
    int p1 = d1 >> 3, u1 = (d1 & 7) ^ (p1 & 7);
    bsrc0 = Bt + (size_t)(n0 + 2 * p0 + (u0 >> 2)) * K_IN + kbeg + (u0 & 3) * 8;
    bsrc1 = Bt + (size_t)(n0 + 2 * p1 + (u1 >> 2)) * K_IN + kbeg + (u1 & 3) * 8;
    bd0 = d0; bd1 = d1;
  }

  float4 A0[2], A1[2], A2[2], A3[2];

#define LOAD_A(S, t) do { \
    S[0] = *(const float4*)(xrow + (t) * 32); \
    S[1] = *(const float4*)(xrow + (t) * 32 + 4); } while (0)
#define WRITE_A(S, t) do { \
    union { __half2 h[4]; uint4 u; } _p; \
    _p.h[0] = __floats2half2_rn(S[0].x, S[0].y); \
    _p.h[1] = __floats2half2_rn(S[0].z, S[0].w); \
    _p.h[2] = __floats2half2_rn(S[1].x, S[1].y); \
    _p.h[3] = __floats2half2_rn(S[1].z, S[1].w); \
    lds[((t) & 1) * 512 + aidx] = _p.u; } while (0)
#define STAGE_B(t) do { \
    int _base = 1024 + ((t) % 3) * 1024; \
    gload_lds16(bsrc0 + (t) * 32, &lds[_base + bd0]); \
    gload_lds16(bsrc1 + (t) * 32, &lds[_base + bd1]); } while (0)

  // prologue: A(0..3) loads, B(0),B(1) stages; vmcnt(2) retires A0-A3 + B0.
  LOAD_A(A0, 0); LOAD_A(A1, 1); LOAD_A(A2, 2); LOAD_A(A3, 3);
  STAGE_B(0); STAGE_B(1);
  WAIT_VM2();
  WRITE_A(A0, 0);
  WAIT_LGKM0();
  BARRIER();

  for (int t = 0; t < NT; ++t) {
    if (t + 2 < NT) STAGE_B(t + 2);
    // compute tile t
    {
      const uint4* Ab = &lds[(t & 1) * 512];
      const uint4* Bb = &lds[1024 + (t % 3) * 1024];
      f16x8 a[4], b[4];
#pragma unroll
      for (int mi = 0; mi < 4; ++mi)
        a[mi] = *(const f16x8*)&Ab[lds_idx(wm * 64 + mi * 16 + fr, fq)];
#pragma unroll
      for (int ni = 0; ni < 4; ++ni)
        b[ni] = *(const f16x8*)&Bb[lds_idx(wn * 64 + ni * 16 + fr, fq)];
#pragma unroll
      for (int mi = 0; mi < 4; ++mi)
#pragma unroll
        for (int ni = 0; ni < 4; ++ni)
          acc[mi][ni] = __builtin_amdgcn_mfma_f32_16x16x32_f16(a[mi], b[ni], acc[mi][ni], 0, 0, 0);
    }
    if (t == NT - 1) break;
    // counted wait: guarantees B(t+1) in LDS (and A(t+1) regs long landed)
    if (t == 0) { WAIT_VM2(); } else if (t < NT - 4) { WAIT_VM4(); } else { WAIT_VM0(); }
    BARRIER();
    // publish A(t+1); refill reg set (t&3) with A(t+4)
    switch ((t + 1) & 3) {
      case 0: WRITE_A(A0, t + 1); break;
      case 1: WRITE_A(A1, t + 1); break;
      case 2: WRITE_A(A2, t + 1); break;
      default: WRITE_A(A3, t + 1); break;
    }
    if (t + 4 < NT) {
      switch (t & 3) {
        case 0: LOAD_A(A0, t + 4); break;
        case 1: LOAD_A(A1, t + 4); break;
        case 2: LOAD_A(A2, t + 4); break;
        default: LOAD_A(A3, t + 4); break;
      }
    }
    WAIT_LGKM0();
    BARRIER();
  }

  __half* Pz = P + (size_t)z * M_TOT * RANK;
#pragma unroll
  for (int mi = 0; mi < 4; ++mi)
#pragma unroll
    for (int ni = 0; ni < 4; ++ni) {
      int col = n0 + wn * 64 + ni * 16 + fr;
      int rbase = m0 + wm * 64 + mi * 16 + fq * 4;
#pragma unroll
      for (int j = 0; j < 4; ++j)
        Pz[(size_t)(rbase + j) * RANK + col] = __float2half_rn(acc[mi][ni][j]);
    }
#undef LOAD_A
#undef WRITE_A
#undef STAGE_B
}

// ---- reduce: t = f16(sum_z P[z]), f32 math, 8 halfs/thread ----
__global__ void k_reduce_t(const uint4* __restrict__ P, uint4* __restrict__ T8, int n8) {
  int i = blockIdx.x * blockDim.x + threadIdx.x;
  if (i >= n8) return;
  float2 f[4] = {};
#pragma unroll
  for (int zz = 0; zz < 4; ++zz) {
    uint4 v = P[(size_t)zz * n8 + i];
    const __half2* h = (const __half2*)&v;
#pragma unroll
    for (int j = 0; j < 4; ++j) {
      float2 g = __half22float2(h[j]);
      f[j].x += g.x; f[j].y += g.y;
    }
  }
  uint4 r;
  __half2* o = (__half2*)&r;
#pragma unroll
  for (int j = 0; j < 4; ++j) o[j] = __floats2half2_rn(f[j].x, f[j].y);
  T8[i] = r;
}

// ---- GEMM2: out = t @ qa^T * scale + bias (unchanged round-6 version) ----
__global__ __launch_bounds__(256, 2) void k_gemm2(
    const __half* __restrict__ T, const __half* __restrict__ QA,
    const float* __restrict__ sa, const float* __restrict__ sb,
    const float* __restrict__ bias, float* __restrict__ Out) {
  __shared__ __align__(16) uint4 lds[2][2048];
  const int tid = threadIdx.x;
  const int lane = tid & 63, wid = tid >> 6, wm = wid & 1, wn = wid >> 1;
  const int flat = blockIdx.x;
  const int xcd = flat & 7, local = flat >> 3;
  const int n_t = xcd * 4 + (local & 3);
  const int m_t = local >> 2;
  const int m0 = m_t * 128, n0 = n_t * 128;
  const int fr = lane & 15, fq = lane >> 4;

  f32x4 acc[4][4] = {};

  auto stage = [&](int kt, int buf) {
#pragma unroll
    for (int c = 0; c < 4; ++c) {
      int d = tid + 256 * c;
      int r = d >> 3, s = (d & 7) ^ (r & 7);
      gload_lds16(T + (size_t)(m0 + r) * RANK + kt * 64 + s * 8, &lds[buf][d]);
    }
#pragma unroll
    for (int c = 0; c < 4; ++c) {
      int d = tid + 256 * c;
      int r = d >> 3, s = (d & 7) ^ (r & 7);
      gload_lds16(QA + (size_t)(n0 + r) * RANK + kt * 64 + s * 8, &lds[buf][1024 + d]);
    }
  };

  stage(0, 0);
  stage(1, 1);
  WAIT_VM8();
  BARRIER();

  const int NT = RANK / 64;
  for (int t = 0; t < NT; ++t) {
    const int cur = t & 1;
#pragma unroll
    for (int kk = 0; kk < 2; ++kk) {
      int s = kk * 4 + fq;
      f16x8 a[4], b[4];
#pragma unroll
      for (int mi = 0; mi < 4; ++mi) {
        int r = wm * 64 + mi * 16 + fr;
        a[mi] = *(const f16x8*)&lds[cur][r * 8 + (s ^ (r & 7))];
      }
#pragma unroll
      for (int ni = 0; ni < 4; ++ni) {
        int n = wn * 64 + ni * 16 + fr;
        b[ni] = *(const f16x8*)&lds[cur][1024 + n * 8 + (s ^ (n & 7))];
      }
#pragma unroll
      for (int mi = 0; mi < 4; ++mi)
#pragma unroll
        for (int ni = 0; ni < 4; ++ni)
          acc[mi][ni] = __builtin_amdgcn_mfma_f32_16x16x32_f16(a[mi], b[ni], acc[mi][ni], 0, 0, 0);
    }
    if (t == NT - 1) break;
    BARRIER();
    if (t + 2 < NT) {
      stage(t + 2, cur);
      WAIT_VM8();
    } else {
      WAIT_VM0();
    }
    BARRIER();
  }

  const float scale = sa[0] * sb[0];
#pragma unroll
  for (int mi = 0; mi < 4; ++mi)
#pragma unroll
    for (int ni = 0; ni < 4; ++ni) {
      int col = n0 + wn * 64 + ni * 16 + fr;
      float bv = bias[col];
      int rbase = m0 + wm * 64 + mi * 16 + fq * 4;
#pragma unroll
      for (int j = 0; j < 4; ++j)
        Out[(size_t)(rbase + j) * N_OUT + col] = acc[mi][ni][j] * scale + bv;
    }
}

extern "C" void kernel_launch(void* const* d_in, const int* in_sizes, int n_in,
                              void* d_out, int out_size, void* d_ws, size_t ws_size,
                              hipStream_t stream) {
  const float* x    = (const float*)d_in[0];
  const int*   qa   = (const int*)d_in[1];
  const int*   qb   = (const int*)d_in[2];
  const float* sa   = (const float*)d_in[3];
  const float* sb   = (const float*)d_in[4];
  const float* bias = (const float*)d_in[5];
  float* out = (float*)d_out;

  char* ws = (char*)d_ws;
  __half* qa_h = (__half*)ws;                  // 4 MB
  __half* qbt  = (__half*)(ws + (4u << 20));   // 4 MB
  __half* t    = (__half*)(ws + (8u << 20));   // 8 MB
  __half* part = (__half*)(ws + (16u << 20));  // 4 x 8 MB f16 partials

  k_cvt_qa<<<2048, 256, 0, stream>>>((const int4*)qa, (ushort4*)qa_h, (N_OUT * RANK) / 4);
  dim3 tg(K_IN / 32, RANK / 32);
  k_transpose_qb<<<tg, 256, 0, stream>>>(qb, qbt);

  k_gemm1_sk<<<512, 512, 0, stream>>>(x, qbt, part);
  const int n8 = M_TOT * RANK / 8;  // 524288
  k_reduce_t<<<n8 / 256, 256, 0, stream>>>((const uint4*)part, (uint4*)t, n8);

  k_gemm2<<<2048, 256, 0, stream>>>(t, qa_h, sa, sb, bias, out);
}

// Round 9
// 141.896 us; speedup vs baseline: 1.1429x; 1.1429x over previous
//
#include <hip/hip_runtime.h>
#include <hip/hip_fp16.h>

// out = sa*sb * (x @ q_b) @ q_a^T + bias
// Round 9: x pre-converted to f16 ONCE; GEMM1 becomes a structural clone of
// the proven GEMM2 kernel (pure global_load_lds both operands, counted
// vmcnt(8) double-buffer, BM=BN=128 BK=64), split-K=4 with f16 partials.
// Rationale: GEMM2 delivers ~14.5 B/cyc/block with this structure; GEMM1's
// f32 reg-staged A-path was the ~3.3 B/cyc serializer across R3-R8.

#define M_TOT 8192
#define N_OUT 4096
#define K_IN  4096
#define RANK  512

typedef _Float16 f16x8 __attribute__((ext_vector_type(8)));
typedef float f32x4 __attribute__((ext_vector_type(4)));

#define WAIT_VM0() asm volatile("s_waitcnt vmcnt(0)" ::: "memory")
#define WAIT_VM8() asm volatile("s_waitcnt vmcnt(8)" ::: "memory")
#define BARRIER() do { __builtin_amdgcn_s_barrier(); __builtin_amdgcn_sched_barrier(0); } while (0)

__device__ __forceinline__ void gload_lds16(const void* g, void* l) {
  __builtin_amdgcn_global_load_lds(
      (const __attribute__((address_space(1))) unsigned int*)g,
      (__attribute__((address_space(3))) unsigned int*)l, 16, 0, 0);
}

// ---- convert x f32 -> f16 (streaming, 8 elems/thread) ----
__global__ void k_cvt_x(const float4* __restrict__ X, uint4* __restrict__ O, int n8) {
  int i = blockIdx.x * blockDim.x + threadIdx.x;
  if (i >= n8) return;
  float4 a = X[2 * i], b = X[2 * i + 1];
  uint4 r;
  __half2* h = (__half2*)&r;
  h[0] = __floats2half2_rn(a.x, a.y);
  h[1] = __floats2half2_rn(a.z, a.w);
  h[2] = __floats2half2_rn(b.x, b.y);
  h[3] = __floats2half2_rn(b.z, b.w);
  O[i] = r;
}

// ---- convert q_a int32 -> fp16 ----
__global__ void k_cvt_qa(const int4* __restrict__ q, ushort4* __restrict__ o, int n4) {
  int i = blockIdx.x * blockDim.x + threadIdx.x;
  if (i >= n4) return;
  int4 v = q[i];
  ushort4 r;
  r.x = __half_as_ushort(__float2half_rn((float)v.x));
  r.y = __half_as_ushort(__float2half_rn((float)v.y));
  r.z = __half_as_ushort(__float2half_rn((float)v.z));
  r.w = __half_as_ushort(__float2half_rn((float)v.w));
  o[i] = r;
}

// ---- transpose q_b [K_IN][RANK] i32 -> qbt [RANK][K_IN] fp16 ----
__global__ void k_transpose_qb(const int* __restrict__ qb, __half* __restrict__ qbt) {
  __shared__ __half tile[32][33];
  int tx = threadIdx.x & 31, ty = threadIdx.x >> 5;
  int k0 = blockIdx.x * 32, r0 = blockIdx.y * 32;
#pragma unroll
  for (int j = 0; j < 4; ++j)
    tile[ty + j * 8][tx] = __float2half_rn((float)qb[(size_t)(k0 + ty + j * 8) * RANK + r0 + tx]);
  __syncthreads();
#pragma unroll
  for (int j = 0; j < 4; ++j)
    qbt[(size_t)(r0 + ty + j * 8) * K_IN + k0 + tx] = tile[tx][ty + j * 8];
}

// ---- GEMM1 (pipelined clone of GEMM2): P[z] = x_h[:,z-chunk] @ qbt[:,z-chunk]^T
// BM=128 BN=128 BK=64, 4 waves (2x2), wave tile 64x64, acc[4][4], NT=16.
// Counted vmcnt(8) dbuf, gload_lds both operands, f16 partial epilogue.
// XCD map: xcd=blk&7 owns (z=xcd>>1, n-pair=xcd&1); local: n_t lsb, m_t rest.
__global__ __launch_bounds__(256, 2) void k_gemm1p(
    const __half* __restrict__ XH, const __half* __restrict__ Bt,
    __half* __restrict__ P) {
  __shared__ __align__(16) uint4 lds[2][2048];
  const int tid = threadIdx.x;
  const int lane = tid & 63, wid = tid >> 6, wm = wid & 1, wn = wid >> 1;
  const int blk = blockIdx.x;
  const int xcd = blk & 7, local = blk >> 3;          // local 0..127
  const int z = xcd >> 1;                             // 0..3
  const int n_t = (xcd & 1) * 2 + (local & 1);        // 0..3
  const int m_t = local >> 1;                         // 0..63
  const int m0 = m_t * 128, n0 = n_t * 128;
  const int kbeg = z * (K_IN / 4);
  const int fr = lane & 15, fq = lane >> 4;

  f32x4 acc[4][4] = {};

  auto stage = [&](int kt, int buf) {
#pragma unroll
    for (int c = 0; c < 4; ++c) {
      int d = tid + 256 * c;
      int r = d >> 3, s = (d & 7) ^ (r & 7);
      gload_lds16(XH + (size_t)(m0 + r) * K_IN + kbeg + kt * 64 + s * 8, &lds[buf][d]);
    }
#pragma unroll
    for (int c = 0; c < 4; ++c) {
      int d = tid + 256 * c;
      int r = d >> 3, s = (d & 7) ^ (r & 7);
      gload_lds16(Bt + (size_t)(n0 + r) * K_IN + kbeg + kt * 64 + s * 8, &lds[buf][1024 + d]);
    }
  };

  stage(0, 0);
  stage(1, 1);
  WAIT_VM8();
  BARRIER();

  const int NT = (K_IN / 4) / 64;  // 16
  for (int t = 0; t < NT; ++t) {
    const int cur = t & 1;
#pragma unroll
    for (int kk = 0; kk < 2; ++kk) {
      int s = kk * 4 + fq;
      f16x8 a[4], b[4];
#pragma unroll
      for (int mi = 0; mi < 4; ++mi) {
        int r = wm * 64 + mi * 16 + fr;
        a[mi] = *(const f16x8*)&lds[cur][r * 8 + (s ^ (r & 7))];
      }
#pragma unroll
      for (int ni = 0; ni < 4; ++ni) {
        int n = wn * 64 + ni * 16 + fr;
        b[ni] = *(const f16x8*)&lds[cur][1024 + n * 8 + (s ^ (n & 7))];
      }
#pragma unroll
      for (int mi = 0; mi < 4; ++mi)
#pragma unroll
        for (int ni = 0; ni < 4; ++ni)
          acc[mi][ni] = __builtin_amdgcn_mfma_f32_16x16x32_f16(a[mi], b[ni], acc[mi][ni], 0, 0, 0);
    }
    if (t == NT - 1) break;
    BARRIER();
    if (t + 2 < NT) {
      stage(t + 2, cur);
      WAIT_VM8();
    } else {
      WAIT_VM0();
    }
    BARRIER();
  }

  __half* Pz = P + (size_t)z * M_TOT * RANK;
#pragma unroll
  for (int mi = 0; mi < 4; ++mi)
#pragma unroll
    for (int ni = 0; ni < 4; ++ni) {
      int col = n0 + wn * 64 + ni * 16 + fr;
      int rbase = m0 + wm * 64 + mi * 16 + fq * 4;
#pragma unroll
      for (int j = 0; j < 4; ++j)
        Pz[(size_t)(rbase + j) * RANK + col] = __float2half_rn(acc[mi][ni][j]);
    }
}

// ---- fallback GEMM1 (R6 best, in-kernel f32->f16 cvt), f16 partials ----
__global__ __launch_bounds__(256, 4) void k_gemm1_fb(
    const float* __restrict__ X, const __half* __restrict__ Bt,
    __half* __restrict__ P) {
  __shared__ __align__(16) uint4 lds[2560];
  const int tid = threadIdx.x;
  const int lane = tid & 63, wn = tid >> 6;
  const int flat = blockIdx.x;
  const int xcd = flat & 7, local = flat >> 3;
  const int z = xcd >> 1;
  const int m_t = (xcd & 1) * 64 + (local >> 1);
  const int n_t = local & 1;
  const int m0 = m_t * 64, n0 = n_t * 256;
  const int kbeg = z * (K_IN / 4);
  const int fr = lane & 15, fq = lane >> 4;

  f32x4 acc[4][4] = {};
  const int ar = tid >> 2, aq = tid & 3;
  const float* xbase = X + (size_t)(m0 + ar) * K_IN + aq * 16;
  const int aslot0 = ar * 8 + ((2 * aq) ^ (ar & 7));
  const int aslot1 = ar * 8 + ((2 * aq + 1) ^ (ar & 7));

  for (int it = 0; it < (K_IN / 4) / 64; ++it) {
    const int k0 = kbeg + it * 64;
#pragma unroll
    for (int c = 0; c < 8; ++c) {
      int d = tid + 256 * c;
      int r = d >> 3, s = (d & 7) ^ (r & 7);
      gload_lds16(Bt + (size_t)(n0 + r) * K_IN + k0 + s * 8, &lds[512 + d]);
    }
    float4 v0 = *(const float4*)(xbase + k0);
    float4 v1 = *(const float4*)(xbase + k0 + 4);
    float4 v2 = *(const float4*)(xbase + k0 + 8);
    float4 v3 = *(const float4*)(xbase + k0 + 12);
    union { __half2 h[4]; uint4 u; } p0, p1;
    p0.h[0] = __floats2half2_rn(v0.x, v0.y);
    p0.h[1] = __floats2half2_rn(v0.z, v0.w);
    p0.h[2] = __floats2half2_rn(v1.x, v1.y);
    p0.h[3] = __floats2half2_rn(v1.z, v1.w);
    p1.h[0] = __floats2half2_rn(v2.x, v2.y);
    p1.h[1] = __floats2half2_rn(v2.z, v2.w);
    p1.h[2] = __floats2half2_rn(v3.x, v3.y);
    p1.h[3] = __floats2half2_rn(v3.z, v3.w);
    lds[aslot0] = p0.u;
    lds[aslot1] = p1.u;
    __syncthreads();
#pragma unroll
    for (int kk = 0; kk < 2; ++kk) {
      const int s = kk * 4 + fq;
      f16x8 a[4], b[4];
#pragma unroll
      for (int mi = 0; mi < 4; ++mi) {
        int r = mi * 16 + fr;
        a[mi] = *(const f16x8*)&lds[r * 8 + (s ^ (r & 7))];
      }
#pragma unroll
      for (int ni = 0; ni < 4; ++ni) {
        int n = wn * 64 + ni * 16 + fr;
        b[ni] = *(const f16x8*)&lds[512 + n * 8 + (s ^ (n & 7))];
      }
#pragma unroll
      for (int mi = 0; mi < 4; ++mi)
#pragma unroll
        for (int ni = 0; ni < 4; ++ni)
          acc[mi][ni] = __builtin_amdgcn_mfma_f32_16x16x32_f16(a[mi], b[ni], acc[mi][ni], 0, 0, 0);
    }
    __syncthreads();
  }

  __half* Pz = P + (size_t)z * M_TOT * RANK;
#pragma unroll
  for (int mi = 0; mi < 4; ++mi)
#pragma unroll
    for (int ni = 0; ni < 4; ++ni) {
      int col = n0 + wn * 64 + ni * 16 + fr;
      int rbase = m0 + mi * 16 + fq * 4;
#pragma unroll
      for (int j = 0; j < 4; ++j)
        Pz[(size_t)(rbase + j) * RANK + col] = __float2half_rn(acc[mi][ni][j]);
    }
}

// ---- reduce: t = f16(sum_z P[z]), f32 math, 8 halfs/thread ----
__global__ void k_reduce_t(const uint4* __restrict__ P, uint4* __restrict__ T8, int n8) {
  int i = blockIdx.x * blockDim.x + threadIdx.x;
  if (i >= n8) return;
  float2 f[4] = {};
#pragma unroll
  for (int zz = 0; zz < 4; ++zz) {
    uint4 v = P[(size_t)zz * n8 + i];
    const __half2* h = (const __half2*)&v;
#pragma unroll
    for (int j = 0; j < 4; ++j) {
      float2 g = __half22float2(h[j]);
      f[j].x += g.x; f[j].y += g.y;
    }
  }
  uint4 r;
  __half2* o = (__half2*)&r;
#pragma unroll
  for (int j = 0; j < 4; ++j) o[j] = __floats2half2_rn(f[j].x, f[j].y);
  T8[i] = r;
}

// ---- GEMM2: out = t @ qa^T * scale + bias (unchanged, proven) ----
__global__ __launch_bounds__(256, 2) void k_gemm2(
    const __half* __restrict__ T, const __half* __restrict__ QA,
    const float* __restrict__ sa, const float* __restrict__ sb,
    const float* __restrict__ bias, float* __restrict__ Out) {
  __shared__ __align__(16) uint4 lds[2][2048];
  const int tid = threadIdx.x;
  const int lane = tid & 63, wid = tid >> 6, wm = wid & 1, wn = wid >> 1;
  const int flat = blockIdx.x;
  const int xcd = flat & 7, local = flat >> 3;
  const int n_t = xcd * 4 + (local & 3);
  const int m_t = local >> 2;
  const int m0 = m_t * 128, n0 = n_t * 128;
  const int fr = lane & 15, fq = lane >> 4;

  f32x4 acc[4][4] = {};

  auto stage = [&](int kt, int buf) {
#pragma unroll
    for (int c = 0; c < 4; ++c) {
      int d = tid + 256 * c;
      int r = d >> 3, s = (d & 7) ^ (r & 7);
      gload_lds16(T + (size_t)(m0 + r) * RANK + kt * 64 + s * 8, &lds[buf][d]);
    }
#pragma unroll
    for (int c = 0; c < 4; ++c) {
      int d = tid + 256 * c;
      int r = d >> 3, s = (d & 7) ^ (r & 7);
      gload_lds16(QA + (size_t)(n0 + r) * RANK + kt * 64 + s * 8, &lds[buf][1024 + d]);
    }
  };

  stage(0, 0);
  stage(1, 1);
  WAIT_VM8();
  BARRIER();

  const int NT = RANK / 64;
  for (int t = 0; t < NT; ++t) {
    const int cur = t & 1;
#pragma unroll
    for (int kk = 0; kk < 2; ++kk) {
      int s = kk * 4 + fq;
      f16x8 a[4], b[4];
#pragma unroll
      for (int mi = 0; mi < 4; ++mi) {
        int r = wm * 64 + mi * 16 + fr;
        a[mi] = *(const f16x8*)&lds[cur][r * 8 + (s ^ (r & 7))];
      }
#pragma unroll
      for (int ni = 0; ni < 4; ++ni) {
        int n = wn * 64 + ni * 16 + fr;
        b[ni] = *(const f16x8*)&lds[cur][1024 + n * 8 + (s ^ (n & 7))];
      }
#pragma unroll
      for (int mi = 0; mi < 4; ++mi)
#pragma unroll
        for (int ni = 0; ni < 4; ++ni)
          acc[mi][ni] = __builtin_amdgcn_mfma_f32_16x16x32_f16(a[mi], b[ni], acc[mi][ni], 0, 0, 0);
    }
    if (t == NT - 1) break;
    BARRIER();
    if (t + 2 < NT) {
      stage(t + 2, cur);
      WAIT_VM8();
    } else {
      WAIT_VM0();
    }
    BARRIER();
  }

  const float scale = sa[0] * sb[0];
#pragma unroll
  for (int mi = 0; mi < 4; ++mi)
#pragma unroll
    for (int ni = 0; ni < 4; ++ni) {
      int col = n0 + wn * 64 + ni * 16 + fr;
      float bv = bias[col];
      int rbase = m0 + wm * 64 + mi * 16 + fq * 4;
#pragma unroll
      for (int j = 0; j < 4; ++j)
        Out[(size_t)(rbase + j) * N_OUT + col] = acc[mi][ni][j] * scale + bv;
    }
}

extern "C" void kernel_launch(void* const* d_in, const int* in_sizes, int n_in,
                              void* d_out, int out_size, void* d_ws, size_t ws_size,
                              hipStream_t stream) {
  const float* x    = (const float*)d_in[0];
  const int*   qa   = (const int*)d_in[1];
  const int*   qb   = (const int*)d_in[2];
  const float* sa   = (const float*)d_in[3];
  const float* sb   = (const float*)d_in[4];
  const float* bias = (const float*)d_in[5];
  float* out = (float*)d_out;

  // layout: qa_h 4MB | qbt 4MB | t 8MB | part 32MB | x_h 64MB  = 112 MiB
  char* ws = (char*)d_ws;
  __half* qa_h = (__half*)ws;
  __half* qbt  = (__half*)(ws + (4u << 20));
  __half* t    = (__half*)(ws + (8u << 20));
  __half* part = (__half*)(ws + (16u << 20));
  __half* x_h  = (__half*)(ws + (48u << 20));

  k_cvt_qa<<<2048, 256, 0, stream>>>((const int4*)qa, (ushort4*)qa_h, (N_OUT * RANK) / 4);
  dim3 tg(K_IN / 32, RANK / 32);
  k_transpose_qb<<<tg, 256, 0, stream>>>(qb, qbt);

  const bool big_ws = ws_size >= (112ull << 20);
  if (big_ws) {
    const int nx8 = M_TOT * K_IN / 8;  // 4,194,304
    k_cvt_x<<<nx8 / 256, 256, 0, stream>>>((const float4*)x, (uint4*)x_h, nx8);
    k_gemm1p<<<1024, 256, 0, stream>>>(x_h, qbt, part);
  } else {
    k_gemm1_fb<<<1024, 256, 0, stream>>>(x, qbt, part);
  }
  const int n8 = M_TOT * RANK / 8;  // 524288
  k_reduce_t<<<n8 / 256, 256, 0, stream>>>((const uint4*)part, (uint4*)t, n8);

  k_gemm2<<<2048, 256, 0, stream>>>(t, qa_h, sa, sb, bias, out);
}

// Round 10
// 133.151 us; speedup vs baseline: 1.2180x; 1.0657x over previous
//
#include <hip/hip_runtime.h>
#include <hip/hip_fp16.h>

// out = sa*sb * (x @ q_b) @ q_a^T + bias
// Round 10: GEMM1 streams x as RAW F32 via global_load_lds (no cvt pre-pass,
// no reg-staging); f32->f16 conversion happens at LDS->register fragment read
// (4 cvt_pk per frag, ~10% VALU overhead). Counted-vmcnt(4) double-buffer
// (GEMM2's proven 14.5 B/cyc structure). BM=128 BN=256 BK=32 SK=4, 8 waves.
// reduce + GEMM2 unchanged (proven).

#define M_TOT 8192
#define N_OUT 4096
#define K_IN  4096
#define RANK  512

typedef _Float16 f16x8 __attribute__((ext_vector_type(8)));
typedef float f32x4 __attribute__((ext_vector_type(4)));

#define WAIT_VM0() asm volatile("s_waitcnt vmcnt(0)" ::: "memory")
#define WAIT_VM4() asm volatile("s_waitcnt vmcnt(4)" ::: "memory")
#define WAIT_VM8() asm volatile("s_waitcnt vmcnt(8)" ::: "memory")
#define BARRIER() do { __builtin_amdgcn_s_barrier(); __builtin_amdgcn_sched_barrier(0); } while (0)

__device__ __forceinline__ void gload_lds16(const void* g, void* l) {
  __builtin_amdgcn_global_load_lds(
      (const __attribute__((address_space(1))) unsigned int*)g,
      (__attribute__((address_space(3))) unsigned int*)l, 16, 0, 0);
}

// ---- convert q_a int32 -> fp16 ----
__global__ void k_cvt_qa(const int4* __restrict__ q, ushort4* __restrict__ o, int n4) {
  int i = blockIdx.x * blockDim.x + threadIdx.x;
  if (i >= n4) return;
  int4 v = q[i];
  ushort4 r;
  r.x = __half_as_ushort(__float2half_rn((float)v.x));
  r.y = __half_as_ushort(__float2half_rn((float)v.y));
  r.z = __half_as_ushort(__float2half_rn((float)v.z));
  r.w = __half_as_ushort(__float2half_rn((float)v.w));
  o[i] = r;
}

// ---- transpose q_b [K_IN][RANK] i32 -> qbt [RANK][K_IN] fp16 ----
__global__ void k_transpose_qb(const int* __restrict__ qb, __half* __restrict__ qbt) {
  __shared__ __half tile[32][33];
  int tx = threadIdx.x & 31, ty = threadIdx.x >> 5;
  int k0 = blockIdx.x * 32, r0 = blockIdx.y * 32;
#pragma unroll
  for (int j = 0; j < 4; ++j)
    tile[ty + j * 8][tx] = __float2half_rn((float)qb[(size_t)(k0 + ty + j * 8) * RANK + r0 + tx]);
  __syncthreads();
#pragma unroll
  for (int j = 0; j < 4; ++j)
    qbt[(size_t)(r0 + ty + j * 8) * K_IN + k0 + tx] = tile[tx][ty + j * 8];
}

// ---- GEMM1: P[z] = x[:,z-chunk] @ qbt[:,z-chunk]^T, f32-A direct DMA ----
// BM=128 BN=256 BK=32, 512 thr = 8 waves (2m x 4n), wave 64x64, acc[4][4].
// LDS per buf: A 128x32 f32 (16KB, 8-slot XOR rows) + B 256x32 f16 (16KB,
// paired-row XOR). dbuf = 64 KB. 4 gload_lds/thread/tile, vmcnt(4) steady.
// XCD map: xcd=blk&7 owns (z=xcd>>1, n_t=xcd&1); local = m_t.
__global__ __launch_bounds__(512, 4) void k_gemm1v(
    const float* __restrict__ X, const __half* __restrict__ Bt,
    __half* __restrict__ P) {
  __shared__ __align__(16) uint4 lds[2][2048];  // [buf][0..1023]=A, [1024..2047]=B
  const int tid = threadIdx.x;
  const int lane = tid & 63, wid = tid >> 6;
  const int wm = wid & 1, wn = wid >> 1;          // 2m x 4n
  const int blk = blockIdx.x;
  const int xcd = blk & 7, m_t = blk >> 3;        // m_t 0..63
  const int z = xcd >> 1, n_t = xcd & 1;
  const int m0 = m_t * 128, n0 = n_t * 256;
  const int kbeg = z * (K_IN / 4);
  const int fr = lane & 15, fq = lane >> 4;

  f32x4 acc[4][4] = {};

  auto stage = [&](int kt, int buf) {
    // A: 128 rows x 8 f32-slots; phys d -> row d>>3, slot (d&7)^(row&7)
#pragma unroll
    for (int c = 0; c < 2; ++c) {
      int d = tid + 512 * c;
      int r = d >> 3, s = (d & 7) ^ (r & 7);
      gload_lds16(X + (size_t)(m0 + r) * K_IN + kbeg + kt * 32 + s * 4, &lds[buf][d]);
    }
    // B: 128 pair-rows x 8 f16-slots; phys d -> p=d>>3, u=(d&7)^(p&7),
    // row = 2p+(u>>2), k-slot = u&3
#pragma unroll
    for (int c = 0; c < 2; ++c) {
      int d = tid + 512 * c;
      int p = d >> 3, u = (d & 7) ^ (p & 7);
      gload_lds16(Bt + (size_t)(n0 + 2 * p + (u >> 2)) * K_IN + kbeg + kt * 32 + (u & 3) * 8,
                  &lds[buf][1024 + d]);
    }
  };

  stage(0, 0);
  stage(1, 1);
  WAIT_VM4();   // tile 0's 4 loads done (tile 1's 4 in flight)
  BARRIER();

  const int NT = (K_IN / 4) / 32;  // 32
  for (int t = 0; t < NT; ++t) {
    const uint4* Ab = &lds[t & 1][0];
    const uint4* Bb = &lds[t & 1][1024];
    f16x8 a[4], b[4];
#pragma unroll
    for (int mi = 0; mi < 4; ++mi) {
      int r = wm * 64 + mi * 16 + fr;
      f32x4 u0 = *(const f32x4*)&Ab[r * 8 + ((fq * 2) ^ (r & 7))];
      f32x4 u1 = *(const f32x4*)&Ab[r * 8 + ((fq * 2 + 1) ^ (r & 7))];
      union { __half2 h[4]; f16x8 v; } pa;
      pa.h[0] = __floats2half2_rn(u0[0], u0[1]);
      pa.h[1] = __floats2half2_rn(u0[2], u0[3]);
      pa.h[2] = __floats2half2_rn(u1[0], u1[1]);
      pa.h[3] = __floats2half2_rn(u1[2], u1[3]);
      a[mi] = pa.v;
    }
#pragma unroll
    for (int ni = 0; ni < 4; ++ni) {
      int r = wn * 64 + ni * 16 + fr;
      int p = r >> 1;
      b[ni] = *(const f16x8*)&Bb[p * 8 + ((((r & 1) << 2) | fq) ^ (p & 7))];
    }
#pragma unroll
    for (int mi = 0; mi < 4; ++mi)
#pragma unroll
      for (int ni = 0; ni < 4; ++ni)
        acc[mi][ni] = __builtin_amdgcn_mfma_f32_16x16x32_f16(a[mi], b[ni], acc[mi][ni], 0, 0, 0);

    if (t == NT - 1) break;
    BARRIER();                       // all waves done reading buf (t+1 parity)
    if (t + 2 < NT) {
      stage(t + 2, t & 1);
      WAIT_VM4();                    // tile t+1's 4 loads landed
    } else {
      WAIT_VM0();
    }
    BARRIER();
  }

  __half* Pz = P + (size_t)z * M_TOT * RANK;
#pragma unroll
  for (int mi = 0; mi < 4; ++mi)
#pragma unroll
    for (int ni = 0; ni < 4; ++ni) {
      int col = n0 + wn * 64 + ni * 16 + fr;
      int rbase = m0 + wm * 64 + mi * 16 + fq * 4;
#pragma unroll
      for (int j = 0; j < 4; ++j)
        Pz[(size_t)(rbase + j) * RANK + col] = __float2half_rn(acc[mi][ni][j]);
    }
}

// ---- fallback GEMM1 (R6 best) for small workspace ----
__global__ __launch_bounds__(256, 4) void k_gemm1_fb(
    const float* __restrict__ X, const __half* __restrict__ Bt,
    __half* __restrict__ P) {
  __shared__ __align__(16) uint4 lds[2560];
  const int tid = threadIdx.x;
  const int lane = tid & 63, wn = tid >> 6;
  const int flat = blockIdx.x;
  const int xcd = flat & 7, local = flat >> 3;
  const int z = xcd >> 1;
  const int m_t = (xcd & 1) * 64 + (local >> 1);
  const int n_t = local & 1;
  const int m0 = m_t * 64, n0 = n_t * 256;
  const int kbeg = z * (K_IN / 4);
  const int fr = lane & 15, fq = lane >> 4;

  f32x4 acc[4][4] = {};
  const int ar = tid >> 2, aq = tid & 3;
  const float* xbase = X + (size_t)(m0 + ar) * K_IN + aq * 16;
  const int aslot0 = ar * 8 + ((2 * aq) ^ (ar & 7));
  const int aslot1 = ar * 8 + ((2 * aq + 1) ^ (ar & 7));

  for (int it = 0; it < (K_IN / 4) / 64; ++it) {
    const int k0 = kbeg + it * 64;
#pragma unroll
    for (int c = 0; c < 8; ++c) {
      int d = tid + 256 * c;
      int r = d >> 3, s = (d & 7) ^ (r & 7);
      gload_lds16(Bt + (size_t)(n0 + r) * K_IN + k0 + s * 8, &lds[512 + d]);
    }
    float4 v0 = *(const float4*)(xbase + k0);
    float4 v1 = *(const float4*)(xbase + k0 + 4);
    float4 v2 = *(const float4*)(xbase + k0 + 8);
    float4 v3 = *(const float4*)(xbase + k0 + 12);
    union { __half2 h[4]; uint4 u; } p0, p1;
    p0.h[0] = __floats2half2_rn(v0.x, v0.y);
    p0.h[1] = __floats2half2_rn(v0.z, v0.w);
    p0.h[2] = __floats2half2_rn(v1.x, v1.y);
    p0.h[3] = __floats2half2_rn(v1.z, v1.w);
    p1.h[0] = __floats2half2_rn(v2.x, v2.y);
    p1.h[1] = __floats2half2_rn(v2.z, v2.w);
    p1.h[2] = __floats2half2_rn(v3.x, v3.y);
    p1.h[3] = __floats2half2_rn(v3.z, v3.w);
    lds[aslot0] = p0.u;
    lds[aslot1] = p1.u;
    __syncthreads();
#pragma unroll
    for (int kk = 0; kk < 2; ++kk) {
      const int s = kk * 4 + fq;
      f16x8 a[4], b[4];
#pragma unroll
      for (int mi = 0; mi < 4; ++mi) {
        int r = mi * 16 + fr;
        a[mi] = *(const f16x8*)&lds[r * 8 + (s ^ (r & 7))];
      }
#pragma unroll
      for (int ni = 0; ni < 4; ++ni) {
        int n = wn * 64 + ni * 16 + fr;
        b[ni] = *(const f16x8*)&lds[512 + n * 8 + (s ^ (n & 7))];
      }
#pragma unroll
      for (int mi = 0; mi < 4; ++mi)
#pragma unroll
        for (int ni = 0; ni < 4; ++ni)
          acc[mi][ni] = __builtin_amdgcn_mfma_f32_16x16x32_f16(a[mi], b[ni], acc[mi][ni], 0, 0, 0);
    }
    __syncthreads();
  }

  __half* Pz = P + (size_t)z * M_TOT * RANK;
#pragma unroll
  for (int mi = 0; mi < 4; ++mi)
#pragma unroll
    for (int ni = 0; ni < 4; ++ni) {
      int col = n0 + wn * 64 + ni * 16 + fr;
      int rbase = m0 + mi * 16 + fq * 4;
#pragma unroll
      for (int j = 0; j < 4; ++j)
        Pz[(size_t)(rbase + j) * RANK + col] = __float2half_rn(acc[mi][ni][j]);
    }
}

// ---- reduce: t = f16(sum_z P[z]), f32 math, 8 halfs/thread ----
__global__ void k_reduce_t(const uint4* __restrict__ P, uint4* __restrict__ T8, int n8) {
  int i = blockIdx.x * blockDim.x + threadIdx.x;
  if (i >= n8) return;
  float2 f[4] = {};
#pragma unroll
  for (int zz = 0; zz < 4; ++zz) {
    uint4 v = P[(size_t)zz * n8 + i];
    const __half2* h = (const __half2*)&v;
#pragma unroll
    for (int j = 0; j < 4; ++j) {
      float2 g = __half22float2(h[j]);
      f[j].x += g.x; f[j].y += g.y;
    }
  }
  uint4 r;
  __half2* o = (__half2*)&r;
#pragma unroll
  for (int j = 0; j < 4; ++j) o[j] = __floats2half2_rn(f[j].x, f[j].y);
  T8[i] = r;
}

// ---- GEMM2: out = t @ qa^T * scale + bias (unchanged, proven) ----
__global__ __launch_bounds__(256, 2) void k_gemm2(
    const __half* __restrict__ T, const __half* __restrict__ QA,
    const float* __restrict__ sa, const float* __restrict__ sb,
    const float* __restrict__ bias, float* __restrict__ Out) {
  __shared__ __align__(16) uint4 lds[2][2048];
  const int tid = threadIdx.x;
  const int lane = tid & 63, wid = tid >> 6, wm = wid & 1, wn = wid >> 1;
  const int flat = blockIdx.x;
  const int xcd = flat & 7, local = flat >> 3;
  const int n_t = xcd * 4 + (local & 3);
  const int m_t = local >> 2;
  const int m0 = m_t * 128, n0 = n_t * 128;
  const int fr = lane & 15, fq = lane >> 4;

  f32x4 acc[4][4] = {};

  auto stage = [&](int kt, int buf) {
#pragma unroll
    for (int c = 0; c < 4; ++c) {
      int d = tid + 256 * c;
      int r = d >> 3, s = (d & 7) ^ (r & 7);
      gload_lds16(T + (size_t)(m0 + r) * RANK + kt * 64 + s * 8, &lds[buf][d]);
    }
#pragma unroll
    for (int c = 0; c < 4; ++c) {
      int d = tid + 256 * c;
      int r = d >> 3, s = (d & 7) ^ (r & 7);
      gload_lds16(QA + (size_t)(n0 + r) * RANK + kt * 64 + s * 8, &lds[buf][1024 + d]);
    }
  };

  stage(0, 0);
  stage(1, 1);
  WAIT_VM8();
  BARRIER();

  const int NT = RANK / 64;
  for (int t = 0; t < NT; ++t) {
    const int cur = t & 1;
#pragma unroll
    for (int kk = 0; kk < 2; ++kk) {
      int s = kk * 4 + fq;
      f16x8 a[4], b[4];
#pragma unroll
      for (int mi = 0; mi < 4; ++mi) {
        int r = wm * 64 + mi * 16 + fr;
        a[mi] = *(const f16x8*)&lds[cur][r * 8 + (s ^ (r & 7))];
      }
#pragma unroll
      for (int ni = 0; ni < 4; ++ni) {
        int n = wn * 64 + ni * 16 + fr;
        b[ni] = *(const f16x8*)&lds[cur][1024 + n * 8 + (s ^ (n & 7))];
      }
#pragma unroll
      for (int mi = 0; mi < 4; ++mi)
#pragma unroll
        for (int ni = 0; ni < 4; ++ni)
          acc[mi][ni] = __builtin_amdgcn_mfma_f32_16x16x32_f16(a[mi], b[ni], acc[mi][ni], 0, 0, 0);
    }
    if (t == NT - 1) break;
    BARRIER();
    if (t + 2 < NT) {
      stage(t + 2, cur);
      WAIT_VM8();
    } else {
      WAIT_VM0();
    }
    BARRIER();
  }

  const float scale = sa[0] * sb[0];
#pragma unroll
  for (int mi = 0; mi < 4; ++mi)
#pragma unroll
    for (int ni = 0; ni < 4; ++ni) {
      int col = n0 + wn * 64 + ni * 16 + fr;
      float bv = bias[col];
      int rbase = m0 + wm * 64 + mi * 16 + fq * 4;
#pragma unroll
      for (int j = 0; j < 4; ++j)
        Out[(size_t)(rbase + j) * N_OUT + col] = acc[mi][ni][j] * scale + bv;
    }
}

extern "C" void kernel_launch(void* const* d_in, const int* in_sizes, int n_in,
                              void* d_out, int out_size, void* d_ws, size_t ws_size,
                              hipStream_t stream) {
  const float* x    = (const float*)d_in[0];
  const int*   qa   = (const int*)d_in[1];
  const int*   qb   = (const int*)d_in[2];
  const float* sa   = (const float*)d_in[3];
  const float* sb   = (const float*)d_in[4];
  const float* bias = (const float*)d_in[5];
  float* out = (float*)d_out;

  // layout: qa_h 4MB | qbt 4MB | t 8MB | part 32MB  = 48 MiB
  char* ws = (char*)d_ws;
  __half* qa_h = (__half*)ws;
  __half* qbt  = (__half*)(ws + (4u << 20));
  __half* t    = (__half*)(ws + (8u << 20));
  __half* part = (__half*)(ws + (16u << 20));

  k_cvt_qa<<<2048, 256, 0, stream>>>((const int4*)qa, (ushort4*)qa_h, (N_OUT * RANK) / 4);
  dim3 tg(K_IN / 32, RANK / 32);
  k_transpose_qb<<<tg, 256, 0, stream>>>(qb, qbt);

  k_gemm1v<<<512, 512, 0, stream>>>(x, qbt, part);

  const int n8 = M_TOT * RANK / 8;  // 524288
  k_reduce_t<<<n8 / 256, 256, 0, stream>>>((const uint4*)part, (uint4*)t, n8);

  k_gemm2<<<2048, 256, 0, stream>>>(t, qa_h, sa, sb, bias, out);
}